// Round 4
// baseline (661.860 us; speedup 1.0000x reference)
//
#include <hip/hip_runtime.h>
#include <float.h>

#define NPTS 8192
#define MPTS 8192
#define FDIM 256

#define BM 128
#define BN 128
#define BK 8
#define TCT (MPTS / BN)   /* 64 column tiles */
#define TRT (NPTS / BM)   /* 64 row tiles */

struct Top2 { float c1, c2; int i1, i2; };

__device__ __forceinline__ void t2_init(Top2& t) {
    t.c1 = FLT_MAX; t.c2 = FLT_MAX; t.i1 = 0x7fffffff; t.i2 = 0x7fffffff;
}

// Lexicographic (dist, idx) top-2: matches jax.lax.top_k stable tie-break
// (equal values -> lower index first).
__device__ __forceinline__ void t2_push(Top2& t, float c, int i) {
    bool lt1 = (c < t.c1) || (c == t.c1 && i < t.i1);
    bool lt2 = (c < t.c2) || (c == t.c2 && i < t.i2);
    if (lt1) {
        t.c2 = t.c1; t.i2 = t.i1; t.c1 = c; t.i1 = i;
    } else if (lt2) {
        t.c2 = c; t.i2 = i;
    }
}

__device__ __forceinline__ void t2_merge(Top2& t, const Top2& o) {
    t2_push(t, o.c1, o.i1);
    t2_push(t, o.c2, o.i2);
}

__device__ __forceinline__ float4 t2_pack(const Top2& t) {
    return make_float4(t.c1, t.c2, __int_as_float(t.i1), __int_as_float(t.i2));
}
__device__ __forceinline__ Top2 t2_unpack(float4 v) {
    Top2 t; t.c1 = v.x; t.c2 = v.y; t.i1 = __float_as_int(v.z); t.i2 = __float_as_int(v.w);
    return t;
}

// Inputs: float32 storage (values are bf16-quantized upstream; storage dtype
// per reference is float32). S[n,m] = sum_f d0[f*N+n] * d1[f*M+m].
// Each block: 128x128 tile of dist = 1.414213*sqrt(max(1-S,1e-6)), then
// per-row / per-col top-2 partials.
__global__ __launch_bounds__(256) void tile_top2(
    const float* __restrict__ d0, const float* __restrict__ d1,
    float4* __restrict__ rowPart, float4* __restrict__ colPart)
{
    __shared__ float As[BK][BM];
    __shared__ float Bs[BK][BN];
    __shared__ float4 red[BM][17];   // +1 float4 pad: conflict-free reduction

    const int t  = threadIdx.x;
    const int tx = t & 15, ty = t >> 4;
    const int ctile = blockIdx.x, rtile = blockIdx.y;
    const int n0 = rtile * BM, m0 = ctile * BN;

    float acc[8][8];
#pragma unroll
    for (int i = 0; i < 8; i++)
#pragma unroll
        for (int j = 0; j < 8; j++) acc[i][j] = 0.0f;

    // staging: BK*BM = 1024 floats per operand, 256 threads -> float4 each
    const int lr = t >> 5;            // 0..7 (K row)
    const int lc = (t & 31) << 2;     // 0,4,...,124

    for (int k0 = 0; k0 < FDIM; k0 += BK) {
        float4 a4 = *(const float4*)&d0[(size_t)(k0 + lr) * NPTS + n0 + lc];
        float4 b4 = *(const float4*)&d1[(size_t)(k0 + lr) * MPTS + m0 + lc];
        __syncthreads();              // previous tile's compute done
        *(float4*)&As[lr][lc] = a4;
        *(float4*)&Bs[lr][lc] = b4;
        __syncthreads();
#pragma unroll
        for (int k = 0; k < BK; k++) {
            float av[8], bv[8];
            *(float4*)&av[0] = *(const float4*)&As[k][ty * 8];
            *(float4*)&av[4] = *(const float4*)&As[k][ty * 8 + 4];
            *(float4*)&bv[0] = *(const float4*)&Bs[k][tx * 8];
            *(float4*)&bv[4] = *(const float4*)&Bs[k][tx * 8 + 4];
#pragma unroll
            for (int i = 0; i < 8; i++)
#pragma unroll
                for (int j = 0; j < 8; j++)
                    acc[i][j] = fmaf(av[i], bv[j], acc[i][j]);
        }
    }
    __syncthreads();

    // comparisons happen in dist space (sqrt rounding can collapse distinct
    // c into equal d -> index tie-break, exactly like the reference)
#pragma unroll
    for (int i = 0; i < 8; i++)
#pragma unroll
        for (int j = 0; j < 8; j++)
            acc[i][j] = 1.414213f * sqrtf(fmaxf(1.0f - acc[i][j], 1e-6f));

    const int r0 = ty * 8, c0 = tx * 8;

    // ---- per-row top-2 (forward) ----
#pragma unroll
    for (int i = 0; i < 8; i++) {
        Top2 rt2; t2_init(rt2);
#pragma unroll
        for (int j = 0; j < 8; j++) t2_push(rt2, acc[i][j], m0 + c0 + j);
        red[r0 + i][tx] = t2_pack(rt2);
    }
    __syncthreads();
    if (t < BM) {
        Top2 m; t2_init(m);
#pragma unroll
        for (int e = 0; e < 16; e++) t2_merge(m, t2_unpack(red[t][e]));
        rowPart[(size_t)ctile * NPTS + n0 + t] = t2_pack(m);
    }
    __syncthreads();

    // ---- per-col top-2 (backward) ----
#pragma unroll
    for (int j = 0; j < 8; j++) {
        Top2 ct2; t2_init(ct2);
#pragma unroll
        for (int i = 0; i < 8; i++) t2_push(ct2, acc[i][j], n0 + r0 + i);
        red[c0 + j][ty] = t2_pack(ct2);
    }
    __syncthreads();
    if (t < BN) {
        Top2 m; t2_init(m);
#pragma unroll
        for (int e = 0; e < 16; e++) t2_merge(m, t2_unpack(red[t][e]));
        colPart[(size_t)rtile * MPTS + m0 + t] = t2_pack(m);
    }
}

__global__ __launch_bounds__(256) void reduce_cols(
    const float4* __restrict__ colPart, int* __restrict__ bck_nn, int* __restrict__ bck_ok)
{
    int m = blockIdx.x * 256 + threadIdx.x;
    Top2 a; t2_init(a);
    for (int rt = 0; rt < TRT; rt++)
        t2_merge(a, t2_unpack(colPart[(size_t)rt * MPTS + m]));
    bck_nn[m] = a.i1;
    bck_ok[m] = ((a.c1 / a.c2) < 1.0f) ? 1 : 0;   // exact ref ratio test, RT=1.0
}

// Output buffer is float32 (mixed int/float tuple coerced to f32; harness
// bf16-rounds both act and ref before absmax). Write plain float values.
__global__ __launch_bounds__(256) void reduce_rows_final(
    const float4* __restrict__ rowPart,
    const int* __restrict__ bck_nn, const int* __restrict__ bck_ok,
    float* __restrict__ out)
{
    int n = blockIdx.x * 256 + threadIdx.x;
    Top2 a; t2_init(a);
    for (int ct = 0; ct < TCT; ct++)
        t2_merge(a, t2_unpack(rowPart[(size_t)ct * NPTS + n]));
    int  fwd = a.i1;
    bool ok  = (a.c1 / a.c2) < 1.0f;
    bool mutual = ok && (bck_ok[fwd] != 0) && (bck_nn[fwd] == n);
    int idx0 = mutual ? fwd : -1;
    out[n]             = (float)idx0;                // indices0
    out[NPTS + n]      = -1.0f;                      // matches1 (all -1)
    out[2 * NPTS + n]  = (idx0 > 0) ? 1.0f : 0.0f;   // mscores0 (strict >0 ref quirk)
    out[3 * NPTS + n]  = 0.0f;                       // mscores1
}

extern "C" void kernel_launch(void* const* d_in, const int* in_sizes, int n_in,
                              void* d_out, int out_size, void* d_ws, size_t ws_size,
                              hipStream_t stream)
{
    const float* d0 = (const float*)d_in[0];   // [1, 256, 8192] float32 storage
    const float* d1 = (const float*)d_in[1];   // [1, 256, 8192] float32 storage
    // keypoints0/1 (d_in[2], d_in[3]) only set output shapes; unused.

    char* ws = (char*)d_ws;
    const size_t rowBytes = (size_t)TCT * NPTS * sizeof(float4);  // 8 MB
    const size_t colBytes = (size_t)TRT * MPTS * sizeof(float4);  // 8 MB
    float4* rowPart = (float4*)ws;
    float4* colPart = (float4*)(ws + rowBytes);
    int*    bck_nn  = (int*)(ws + rowBytes + colBytes);
    int*    bck_ok  = bck_nn + MPTS;

    dim3 g1(TCT, TRT);
    tile_top2<<<g1, 256, 0, stream>>>(d0, d1, rowPart, colPart);
    reduce_cols<<<MPTS / 256, 256, 0, stream>>>(colPart, bck_nn, bck_ok);
    reduce_rows_final<<<NPTS / 256, 256, 0, stream>>>(rowPart, bck_nn, bck_ok,
                                                      (float*)d_out);
}

// Round 5
// 571.613 us; speedup vs baseline: 1.1579x; 1.1579x over previous
//
#include <hip/hip_runtime.h>
#include <float.h>

#define NPTS 8192
#define MPTS 8192
#define FDIM 256

#define BM 128
#define BN 128
#define BK 32
#define TCT (MPTS / BN)   /* 64 column tiles */
#define TRT (NPTS / BM)   /* 64 row tiles */

typedef unsigned short ushort_t;
typedef __attribute__((ext_vector_type(8))) short short8;
typedef __attribute__((ext_vector_type(4))) float floatx4;

struct Top2 { float c1, c2; int i1, i2; };

__device__ __forceinline__ void t2_init(Top2& t) {
    t.c1 = FLT_MAX; t.c2 = FLT_MAX; t.i1 = 0x7fffffff; t.i2 = 0x7fffffff;
}
// Lexicographic (dist, idx) top-2, matches jax.lax.top_k stable tie-break.
__device__ __forceinline__ void t2_push(Top2& t, float c, int i) {
    bool lt1 = (c < t.c1) || (c == t.c1 && i < t.i1);
    bool lt2 = (c < t.c2) || (c == t.c2 && i < t.i2);
    if (lt1) { t.c2 = t.c1; t.i2 = t.i1; t.c1 = c; t.i1 = i; }
    else if (lt2) { t.c2 = c; t.i2 = i; }
}
__device__ __forceinline__ void t2_merge(Top2& t, const Top2& o) {
    t2_push(t, o.c1, o.i1); t2_push(t, o.c2, o.i2);
}
__device__ __forceinline__ float4 t2_pack(const Top2& t) {
    return make_float4(t.c1, t.c2, __int_as_float(t.i1), __int_as_float(t.i2));
}
__device__ __forceinline__ Top2 t2_unpack(float4 v) {
    Top2 t; t.c1 = v.x; t.c2 = v.y; t.i1 = __float_as_int(v.z); t.i2 = __float_as_int(v.w);
    return t;
}
__device__ __forceinline__ Top2 t2_shfl_xor(const Top2& a, int mask) {
    Top2 r;
    r.c1 = __shfl_xor(a.c1, mask); r.c2 = __shfl_xor(a.c2, mask);
    r.i1 = __shfl_xor(a.i1, mask); r.i2 = __shfl_xor(a.i2, mask);
    return r;
}

__device__ __forceinline__ float bf2f(ushort_t u) {
    union { unsigned int i; float f; } v; v.i = ((unsigned int)u) << 16; return v.f;
}
__device__ __forceinline__ ushort_t f2bf_rtne(float x) {   // RTNE, no NaN expected
    unsigned int u = __float_as_uint(x);
    unsigned int r = u + 0x7FFFu + ((u >> 16) & 1u);
    return (ushort_t)(r >> 16);
}

// -------- transpose + hi/lo split: src f32 [FDIM][N] -> hiT/loT bf16 [N][FDIM]
// hi = bf16(x) (exact if dataset values are bf16-quantized -> lo == 0 everywhere)
// lo = bf16((x - hi) * 256)
__global__ __launch_bounds__(256) void transpose_split(
    const float* __restrict__ src, ushort_t* __restrict__ hiT,
    ushort_t* __restrict__ loT, int* __restrict__ any_lo_flag, int npts)
{
    __shared__ ushort_t hiS[64][66];   // [n_local][f_local], +2 pad
    __shared__ ushort_t loS[64][66];
    const int t = threadIdx.x;
    const int n0 = blockIdx.x * 64, f0 = blockIdx.y * 64;
    int any_lo = 0;
#pragma unroll
    for (int p = 0; p < 16; p++) {
        int fl = (t >> 6) + p * 4;          // 0..63
        int nl = t & 63;
        float x = src[(size_t)(f0 + fl) * npts + n0 + nl];
        ushort_t hb = f2bf_rtne(x);
        float lo = (x - bf2f(hb)) * 256.0f;
        ushort_t lb = f2bf_rtne(lo);
        if (lb & 0x7FFF) any_lo = 1;
        hiS[nl][fl] = hb;
        loS[nl][fl] = lb;
    }
    __syncthreads();
#pragma unroll
    for (int p = 0; p < 8; p++) {
        int nl = (t >> 5) + p * 8;          // 0..63
        int fp = (t & 31) * 2;              // even f
        unsigned int hw = (unsigned int)hiS[nl][fp] | ((unsigned int)hiS[nl][fp + 1] << 16);
        unsigned int lw = (unsigned int)loS[nl][fp] | ((unsigned int)loS[nl][fp + 1] << 16);
        size_t o = (size_t)(n0 + nl) * FDIM + f0 + fp;
        *(unsigned int*)&hiT[o] = hw;
        *(unsigned int*)&loT[o] = lw;
    }
    if (any_lo) atomicOr(any_lo_flag, 1);
}

#define GLDS(g, l) __builtin_amdgcn_global_load_lds( \
    (const __attribute__((address_space(1))) void*)(g), \
    (__attribute__((address_space(3))) void*)(l), 16, 0, 0)

// -------- fused MFMA GEMM + top-2 tile kernel --------
// hiA/loA: [NPTS][FDIM] bf16 (k-contiguous), hiB/loB: [MPTS][FDIM].
// S[n][m] = hi.hi + (hi.lo + lo.hi)/256; dist = 1.414213*sqrt(max(1-S,1e-6)).
__global__ __launch_bounds__(256, 2) void gemm_top2(
    const ushort_t* __restrict__ hiA, const ushort_t* __restrict__ loA,
    const ushort_t* __restrict__ hiB, const ushort_t* __restrict__ loB,
    const int* __restrict__ any_lo_flag,
    float4* __restrict__ rowPart, float4* __restrict__ colPart)
{
    __shared__ ushort_t Ah[BM * BK];   // 8 KB, row-major [row][k], 64 B rows
    __shared__ ushort_t Bh[BN * BK];
    __shared__ ushort_t Al[BM * BK];
    __shared__ ushort_t Bl[BN * BK];
    __shared__ float4 redR[128][2];
    __shared__ float4 redC[128][2];

    const int t = threadIdx.x;
    const int lane = t & 63, lc = lane & 15, q = lane >> 4;
    const int w = t >> 6, wx = w & 1, wy = w >> 1;
    const int ctile = blockIdx.x, rtile = blockIdx.y;
    const int n0 = rtile * BM, m0 = ctile * BN;

    const bool split = (*any_lo_flag != 0);

    floatx4 acc_hh[4][4], acc_x[4][4];
#pragma unroll
    for (int i = 0; i < 4; i++)
#pragma unroll
        for (int j = 0; j < 4; j++) { acc_hh[i][j] = (floatx4)0.0f; acc_x[i][j] = (floatx4)0.0f; }

    // staging map: thread t covers LDS bytes [t*16, t*16+16) of each half-tile;
    // row = t>>2 (+64 for pass 1), k-offset = (t&3)*8 elements.
    const int srow = t >> 2, skoff = (t & 3) * 8;
    const size_t sldsOff = (size_t)t * 8;           // ushort index = t*8 -> byte t*16

    for (int k0 = 0; k0 < FDIM; k0 += BK) {
        if (k0) __syncthreads();
        {
            const ushort_t* gA0 = hiA + (size_t)(n0 + srow) * FDIM + k0 + skoff;
            const ushort_t* gA1 = hiA + (size_t)(n0 + srow + 64) * FDIM + k0 + skoff;
            const ushort_t* gB0 = hiB + (size_t)(m0 + srow) * FDIM + k0 + skoff;
            const ushort_t* gB1 = hiB + (size_t)(m0 + srow + 64) * FDIM + k0 + skoff;
            GLDS(gA0, Ah + sldsOff);
            GLDS(gA1, Ah + 2048 + sldsOff);
            GLDS(gB0, Bh + sldsOff);
            GLDS(gB1, Bh + 2048 + sldsOff);
            if (split) {
                GLDS(loA + (size_t)(n0 + srow) * FDIM + k0 + skoff, Al + sldsOff);
                GLDS(loA + (size_t)(n0 + srow + 64) * FDIM + k0 + skoff, Al + 2048 + sldsOff);
                GLDS(loB + (size_t)(m0 + srow) * FDIM + k0 + skoff, Bl + sldsOff);
                GLDS(loB + (size_t)(m0 + srow + 64) * FDIM + k0 + skoff, Bl + 2048 + sldsOff);
            }
        }
        __syncthreads();   // compiler emits vmcnt(0) drain before barrier

        short8 ah[4], bh[4];
#pragma unroll
        for (int i = 0; i < 4; i++)
            ah[i] = *(const short8*)&Ah[(size_t)(wy * 64 + i * 16 + lc) * BK + q * 8];
#pragma unroll
        for (int j = 0; j < 4; j++)
            bh[j] = *(const short8*)&Bh[(size_t)(wx * 64 + j * 16 + lc) * BK + q * 8];
#pragma unroll
        for (int i = 0; i < 4; i++)
#pragma unroll
            for (int j = 0; j < 4; j++)
                acc_hh[i][j] = __builtin_amdgcn_mfma_f32_16x16x32_bf16(
                    ah[i], bh[j], acc_hh[i][j], 0, 0, 0);
        if (split) {
            short8 al[4], bl[4];
#pragma unroll
            for (int i = 0; i < 4; i++)
                al[i] = *(const short8*)&Al[(size_t)(wy * 64 + i * 16 + lc) * BK + q * 8];
#pragma unroll
            for (int j = 0; j < 4; j++)
                bl[j] = *(const short8*)&Bl[(size_t)(wx * 64 + j * 16 + lc) * BK + q * 8];
#pragma unroll
            for (int i = 0; i < 4; i++)
#pragma unroll
                for (int j = 0; j < 4; j++) {
                    acc_x[i][j] = __builtin_amdgcn_mfma_f32_16x16x32_bf16(
                        ah[i], bl[j], acc_x[i][j], 0, 0, 0);
                    acc_x[i][j] = __builtin_amdgcn_mfma_f32_16x16x32_bf16(
                        al[i], bh[j], acc_x[i][j], 0, 0, 0);
                }
        }
    }

    // C/D layout (verified m89/m91): within 16x16 tile, S-row = q*4+reg,
    // S-col = lane&15. Convert to dist (same math as round-4-verified kernel).
    float dv[4][4][4];
#pragma unroll
    for (int i = 0; i < 4; i++)
#pragma unroll
        for (int j = 0; j < 4; j++)
#pragma unroll
            for (int r = 0; r < 4; r++) {
                float s = acc_hh[i][j][r] + acc_x[i][j][r] * (1.0f / 256.0f);
                dv[i][j][r] = 1.414213f * sqrtf(fmaxf(1.0f - s, 1e-6f));
            }

    // ---- per-row top-2: reduce across 16 lanes (same q), 4 j-tiles each ----
#pragma unroll
    for (int i = 0; i < 4; i++)
#pragma unroll
        for (int r = 0; r < 4; r++) {
            Top2 p; t2_init(p);
#pragma unroll
            for (int j = 0; j < 4; j++)
                t2_push(p, dv[i][j][r], m0 + wx * 64 + j * 16 + lc);
#pragma unroll
            for (int mask = 1; mask < 16; mask <<= 1) {
                Top2 o = t2_shfl_xor(p, mask); t2_merge(p, o);
            }
            if (lc == 0) redR[wy * 64 + i * 16 + q * 4 + r][wx] = t2_pack(p);
        }

    // ---- per-col top-2: per lane 16 rows, reduce across quads (xor 16,32) ----
#pragma unroll
    for (int j = 0; j < 4; j++) {
        Top2 p; t2_init(p);
#pragma unroll
        for (int i = 0; i < 4; i++)
#pragma unroll
            for (int r = 0; r < 4; r++)
                t2_push(p, dv[i][j][r], n0 + wy * 64 + i * 16 + q * 4 + r);
        Top2 o = t2_shfl_xor(p, 16); t2_merge(p, o);
        o = t2_shfl_xor(p, 32); t2_merge(p, o);
        if (q == 0) redC[wx * 64 + j * 16 + lc][wy] = t2_pack(p);
    }
    __syncthreads();

    if (t < 128) {
        Top2 m = t2_unpack(redR[t][0]);
        t2_merge(m, t2_unpack(redR[t][1]));
        rowPart[(size_t)ctile * NPTS + n0 + t] = t2_pack(m);
    } else {
        int tt = t - 128;
        Top2 m = t2_unpack(redC[tt][0]);
        t2_merge(m, t2_unpack(redC[tt][1]));
        colPart[(size_t)rtile * MPTS + m0 + tt] = t2_pack(m);
    }
}

__global__ __launch_bounds__(256) void reduce_cols(
    const float4* __restrict__ colPart, int* __restrict__ bck_nn, int* __restrict__ bck_ok)
{
    int m = blockIdx.x * 256 + threadIdx.x;
    Top2 a; t2_init(a);
    for (int rt = 0; rt < TRT; rt++)
        t2_merge(a, t2_unpack(colPart[(size_t)rt * MPTS + m]));
    bck_nn[m] = a.i1;
    bck_ok[m] = ((a.c1 / a.c2) < 1.0f) ? 1 : 0;   // exact ref ratio test, RT=1.0
}

__global__ __launch_bounds__(256) void reduce_rows_final(
    const float4* __restrict__ rowPart,
    const int* __restrict__ bck_nn, const int* __restrict__ bck_ok,
    float* __restrict__ out)
{
    int n = blockIdx.x * 256 + threadIdx.x;
    Top2 a; t2_init(a);
    for (int ct = 0; ct < TCT; ct++)
        t2_merge(a, t2_unpack(rowPart[(size_t)ct * NPTS + n]));
    int  fwd = a.i1;
    bool ok  = (a.c1 / a.c2) < 1.0f;
    bool mutual = ok && (bck_ok[fwd] != 0) && (bck_nn[fwd] == n);
    int idx0 = mutual ? fwd : -1;
    out[n]             = (float)idx0;                // indices0
    out[NPTS + n]      = -1.0f;                      // matches1 (all -1)
    out[2 * NPTS + n]  = (idx0 > 0) ? 1.0f : 0.0f;   // mscores0 (strict >0 ref quirk)
    out[3 * NPTS + n]  = 0.0f;                       // mscores1
}

extern "C" void kernel_launch(void* const* d_in, const int* in_sizes, int n_in,
                              void* d_out, int out_size, void* d_ws, size_t ws_size,
                              hipStream_t stream)
{
    const float* d0 = (const float*)d_in[0];   // [1, 256, 8192] f32
    const float* d1 = (const float*)d_in[1];   // [1, 256, 8192] f32

    char* ws = (char*)d_ws;
    const size_t matB = (size_t)NPTS * FDIM * sizeof(ushort_t);      // 4 MB
    ushort_t* hiA = (ushort_t*)(ws);
    ushort_t* loA = (ushort_t*)(ws + matB);
    ushort_t* hiB = (ushort_t*)(ws + 2 * matB);
    ushort_t* loB = (ushort_t*)(ws + 3 * matB);
    char* p = ws + 4 * matB;
    const size_t rowBytes = (size_t)TCT * NPTS * sizeof(float4);     // 8 MB
    const size_t colBytes = (size_t)TRT * MPTS * sizeof(float4);     // 8 MB
    float4* rowPart = (float4*)p;
    float4* colPart = (float4*)(p + rowBytes);
    int*    bck_nn  = (int*)(p + rowBytes + colBytes);
    int*    bck_ok  = bck_nn + MPTS;
    int*    flag    = bck_ok + MPTS;

    hipMemsetAsync(flag, 0, sizeof(int), stream);

    dim3 gt(NPTS / 64, FDIM / 64);
    transpose_split<<<gt, 256, 0, stream>>>(d0, hiA, loA, flag, NPTS);
    transpose_split<<<gt, 256, 0, stream>>>(d1, hiB, loB, flag, MPTS);

    dim3 g1(TCT, TRT);
    gemm_top2<<<g1, 256, 0, stream>>>(hiA, loA, hiB, loB, flag, rowPart, colPart);
    reduce_cols<<<MPTS / 256, 256, 0, stream>>>(colPart, bck_nn, bck_ok);
    reduce_rows_final<<<NPTS / 256, 256, 0, stream>>>(rowPart, bck_nn, bck_ok,
                                                      (float*)d_out);
}

// Round 6
// 288.642 us; speedup vs baseline: 2.2930x; 1.9804x over previous
//
#include <hip/hip_runtime.h>
#include <float.h>

#define NPTS 8192
#define MPTS 8192
#define FDIM 256

#define BM 128
#define BN 128
#define BK 32
#define TCT (MPTS / BN)   /* 64 column tiles */
#define TRT (NPTS / BM)   /* 64 row tiles */

typedef unsigned short ushort_t;
typedef unsigned int u32;
typedef unsigned long long u64;
typedef __attribute__((ext_vector_type(8))) short short8;
typedef __attribute__((ext_vector_type(4))) float floatx4;

// ---- packed top-2: key = (dist_bits << 32) | idx  (dist > 0 so uint order
// == float order; u64 compare == lexicographic (dist, idx) == jax top_k
// stable tie-break; keys unique -> any merge order is exact) ----
struct KT { u64 k1, k2; };   // k1 <= k2

__device__ __forceinline__ KT kt_sent() { KT a; a.k1 = ~0ull; a.k2 = ~0ull; return a; }
__device__ __forceinline__ KT kt_of_pair(u64 a, u64 b) {
    KT t; bool c = a < b; t.k1 = c ? a : b; t.k2 = c ? b : a; return t;
}
__device__ __forceinline__ KT kt_merge(KT a, KT b) {
    KT r; bool c = a.k1 < b.k1;
    r.k1 = c ? a.k1 : b.k1;
    u64 x = c ? b.k1 : a.k1;     // max of firsts
    u64 y = c ? a.k2 : b.k2;     // runner-up of winning side
    r.k2 = x < y ? x : y;
    return r;
}
__device__ __forceinline__ uint4 kt_pack(KT a) {
    return make_uint4((u32)a.k1, (u32)(a.k1 >> 32), (u32)a.k2, (u32)(a.k2 >> 32));
}
__device__ __forceinline__ KT kt_unpack(uint4 v) {
    KT a; a.k1 = v.x | ((u64)v.y << 32); a.k2 = v.z | ((u64)v.w << 32); return a;
}
__device__ __forceinline__ u64 shfl_xor_u64(u64 v, int m) {
    u32 lo = __shfl_xor((u32)v, m);
    u32 hi = __shfl_xor((u32)(v >> 32), m);
    return ((u64)hi << 32) | lo;
}
__device__ __forceinline__ u64 mk_key(float d, int idx) {
    return ((u64)__float_as_uint(d) << 32) | (u32)idx;
}

__device__ __forceinline__ float bf2f(ushort_t u) {
    union { u32 i; float f; } v; v.i = ((u32)u) << 16; return v.f;
}
__device__ __forceinline__ ushort_t f2bf_rtne(float x) {
    u32 u = __float_as_uint(x);
    u32 r = u + 0x7FFFu + ((u >> 16) & 1u);
    return (ushort_t)(r >> 16);
}

// -------- transpose + hi/lo split (unchanged, proven) --------
__global__ __launch_bounds__(256) void transpose_split(
    const float* __restrict__ src, ushort_t* __restrict__ hiT,
    ushort_t* __restrict__ loT, int* __restrict__ any_lo_flag, int npts)
{
    __shared__ ushort_t hiS[64][66];
    __shared__ ushort_t loS[64][66];
    const int t = threadIdx.x;
    const int n0 = blockIdx.x * 64, f0 = blockIdx.y * 64;
    int any_lo = 0;
#pragma unroll
    for (int p = 0; p < 16; p++) {
        int fl = (t >> 6) + p * 4;
        int nl = t & 63;
        float x = src[(size_t)(f0 + fl) * npts + n0 + nl];
        ushort_t hb = f2bf_rtne(x);
        float lo = (x - bf2f(hb)) * 256.0f;
        ushort_t lb = f2bf_rtne(lo);
        if (lb & 0x7FFF) any_lo = 1;
        hiS[nl][fl] = hb;
        loS[nl][fl] = lb;
    }
    __syncthreads();
#pragma unroll
    for (int p = 0; p < 8; p++) {
        int nl = (t >> 5) + p * 8;
        int fp = (t & 31) * 2;
        u32 hw = (u32)hiS[nl][fp] | ((u32)hiS[nl][fp + 1] << 16);
        u32 lw = (u32)loS[nl][fp] | ((u32)loS[nl][fp + 1] << 16);
        size_t o = (size_t)(n0 + nl) * FDIM + f0 + fp;
        *(u32*)&hiT[o] = hw;
        *(u32*)&loT[o] = lw;
    }
    if (any_lo) atomicOr(any_lo_flag, 1);
}

#define GLDS(g, l) __builtin_amdgcn_global_load_lds( \
    (const __attribute__((address_space(1))) void*)(g), \
    (__attribute__((address_space(3))) void*)(l), 16, 0, 0)

// -------- fused MFMA GEMM + branchless packed top-2 --------
__global__ __launch_bounds__(256, 2) void gemm_top2(
    const ushort_t* __restrict__ hiA, const ushort_t* __restrict__ loA,
    const ushort_t* __restrict__ hiB, const ushort_t* __restrict__ loB,
    const int* __restrict__ any_lo_flag,
    uint4* __restrict__ rowPart, uint4* __restrict__ colPart)
{
    __shared__ char smem[36864];
    ushort_t* Ah = (ushort_t*)smem;                 // 8 KB each
    ushort_t* Bh = (ushort_t*)(smem + 8192);
    ushort_t* Al = (ushort_t*)(smem + 16384);
    ushort_t* Bl = (ushort_t*)(smem + 24576);
    uint4* redC  = (uint4*)(smem + 32768);          // [128][2], 4 KB
    // row-reduction scratch (aliases staging, used only after K-loop):
    u64* scrK1 = (u64*)smem;                        // 2048 u64 = 16 KB
    u64* scrK2 = (u64*)(smem + 16384);              // 16 KB

    const int t = threadIdx.x;
    const int lane = t & 63, lc = lane & 15, q = lane >> 4;
    const int w = t >> 6, wx = w & 1, wy = w >> 1;
    const int ctile = blockIdx.x, rtile = blockIdx.y;
    const int n0 = rtile * BM, m0 = ctile * BN;

    const bool split = (*any_lo_flag != 0);

    floatx4 acc_hh[4][4], acc_x[4][4];
#pragma unroll
    for (int i = 0; i < 4; i++)
#pragma unroll
        for (int j = 0; j < 4; j++) { acc_hh[i][j] = (floatx4)0.0f; acc_x[i][j] = (floatx4)0.0f; }

    const int srow = t >> 2, skoff = (t & 3) * 8;
    const size_t sldsOff = (size_t)t * 8;

    for (int k0 = 0; k0 < FDIM; k0 += BK) {
        if (k0) __syncthreads();
        {
            GLDS(hiA + (size_t)(n0 + srow) * FDIM + k0 + skoff, Ah + sldsOff);
            GLDS(hiA + (size_t)(n0 + srow + 64) * FDIM + k0 + skoff, Ah + 2048 + sldsOff);
            GLDS(hiB + (size_t)(m0 + srow) * FDIM + k0 + skoff, Bh + sldsOff);
            GLDS(hiB + (size_t)(m0 + srow + 64) * FDIM + k0 + skoff, Bh + 2048 + sldsOff);
            if (split) {
                GLDS(loA + (size_t)(n0 + srow) * FDIM + k0 + skoff, Al + sldsOff);
                GLDS(loA + (size_t)(n0 + srow + 64) * FDIM + k0 + skoff, Al + 2048 + sldsOff);
                GLDS(loB + (size_t)(m0 + srow) * FDIM + k0 + skoff, Bl + sldsOff);
                GLDS(loB + (size_t)(m0 + srow + 64) * FDIM + k0 + skoff, Bl + 2048 + sldsOff);
            }
        }
        __syncthreads();

        short8 ah[4], bh[4];
#pragma unroll
        for (int i = 0; i < 4; i++)
            ah[i] = *(const short8*)&Ah[(size_t)(wy * 64 + i * 16 + lc) * BK + q * 8];
#pragma unroll
        for (int j = 0; j < 4; j++)
            bh[j] = *(const short8*)&Bh[(size_t)(wx * 64 + j * 16 + lc) * BK + q * 8];
#pragma unroll
        for (int i = 0; i < 4; i++)
#pragma unroll
            for (int j = 0; j < 4; j++)
                acc_hh[i][j] = __builtin_amdgcn_mfma_f32_16x16x32_bf16(
                    ah[i], bh[j], acc_hh[i][j], 0, 0, 0);
        if (split) {
            short8 al[4], bl[4];
#pragma unroll
            for (int i = 0; i < 4; i++)
                al[i] = *(const short8*)&Al[(size_t)(wy * 64 + i * 16 + lc) * BK + q * 8];
#pragma unroll
            for (int j = 0; j < 4; j++)
                bl[j] = *(const short8*)&Bl[(size_t)(wx * 64 + j * 16 + lc) * BK + q * 8];
#pragma unroll
            for (int i = 0; i < 4; i++)
#pragma unroll
                for (int j = 0; j < 4; j++) {
                    acc_x[i][j] = __builtin_amdgcn_mfma_f32_16x16x32_bf16(
                        ah[i], bl[j], acc_x[i][j], 0, 0, 0);
                    acc_x[i][j] = __builtin_amdgcn_mfma_f32_16x16x32_bf16(
                        al[i], bh[j], acc_x[i][j], 0, 0, 0);
                }
        }
    }

    // ---- epilogue: C/D layout row = q*4+reg, col = lane&15 (verified) ----
    KT colT[4];
#pragma unroll
    for (int j = 0; j < 4; j++) colT[j] = kt_sent();
    KT rowT[4][4];

#pragma unroll
    for (int i = 0; i < 4; i++) {
        float dl[4][4];
#pragma unroll
        for (int j = 0; j < 4; j++)
#pragma unroll
            for (int r = 0; r < 4; r++) {
                float s = acc_hh[i][j][r] + acc_x[i][j][r] * (1.0f / 256.0f);
                dl[j][r] = 1.414213f * sqrtf(fmaxf(1.0f - s, 1e-6f));
            }
        // rows: per r, tournament over the 4 j-columns (payload = col idx)
#pragma unroll
        for (int r = 0; r < 4; r++) {
            u64 v0 = mk_key(dl[0][r], m0 + wx * 64 +  0 + lc);
            u64 v1 = mk_key(dl[1][r], m0 + wx * 64 + 16 + lc);
            u64 v2 = mk_key(dl[2][r], m0 + wx * 64 + 32 + lc);
            u64 v3 = mk_key(dl[3][r], m0 + wx * 64 + 48 + lc);
            rowT[i][r] = kt_merge(kt_of_pair(v0, v1), kt_of_pair(v2, v3));
        }
        // cols: per j, tournament over the 4 r-rows, fold into running colT
        const int rbase = n0 + wy * 64 + i * 16 + q * 4;
#pragma unroll
        for (int j = 0; j < 4; j++) {
            u64 v0 = mk_key(dl[j][0], rbase + 0);
            u64 v1 = mk_key(dl[j][1], rbase + 1);
            u64 v2 = mk_key(dl[j][2], rbase + 2);
            u64 v3 = mk_key(dl[j][3], rbase + 3);
            colT[j] = kt_merge(colT[j], kt_merge(kt_of_pair(v0, v1), kt_of_pair(v2, v3)));
        }
    }

    // cols: merge across the 4 quads (rows q*4+r differ, col lc fixed)
#pragma unroll
    for (int j = 0; j < 4; j++) {
        KT o;
        o.k1 = shfl_xor_u64(colT[j].k1, 16); o.k2 = shfl_xor_u64(colT[j].k2, 16);
        colT[j] = kt_merge(colT[j], o);
        o.k1 = shfl_xor_u64(colT[j].k1, 32); o.k2 = shfl_xor_u64(colT[j].k2, 32);
        colT[j] = kt_merge(colT[j], o);
        if (q == 0) redC[(wx * 64 + j * 16 + lc) * 2 + wy] = kt_pack(colT[j]);
    }

    // rows: two LDS rounds (by wy) over reused staging scratch
#pragma unroll
    for (int round = 0; round < 2; round++) {
        __syncthreads();
        if (wy == round) {
#pragma unroll
            for (int i = 0; i < 4; i++)
#pragma unroll
                for (int r = 0; r < 4; r++) {
                    int row = i * 16 + q * 4 + r;                 // 0..63
                    int col = (lc << 1) | wx;                     // 0..31
                    int slot = (row << 5) | ((col + row) & 31);   // bank swizzle
                    scrK1[slot] = rowT[i][r].k1;
                    scrK2[slot] = rowT[i][r].k2;
                }
        }
        __syncthreads();
        {
            int row = t >> 2, chunk = t & 3;
            KT a = kt_sent();
#pragma unroll
            for (int s = 0; s < 8; s++) {
                int slot = (row << 5) | (chunk << 3) | ((s + row) & 7);
                KT b; b.k1 = scrK1[slot]; b.k2 = scrK2[slot];
                a = kt_merge(a, b);
            }
            KT o;
            o.k1 = shfl_xor_u64(a.k1, 1); o.k2 = shfl_xor_u64(a.k2, 1); a = kt_merge(a, o);
            o.k1 = shfl_xor_u64(a.k1, 2); o.k2 = shfl_xor_u64(a.k2, 2); a = kt_merge(a, o);
            if (chunk == 0)
                rowPart[(size_t)ctile * NPTS + n0 + round * 64 + row] = kt_pack(a);
        }
    }

    // cols final: merge the two wy halves
    __syncthreads();
    if (t < 128) {
        KT m = kt_unpack(redC[t * 2 + 0]);
        m = kt_merge(m, kt_unpack(redC[t * 2 + 1]));
        colPart[(size_t)rtile * MPTS + m0 + t] = kt_pack(m);
    }
}

__global__ __launch_bounds__(256) void reduce_cols(
    const uint4* __restrict__ colPart, int* __restrict__ bck_nn, int* __restrict__ bck_ok)
{
    int m = blockIdx.x * 256 + threadIdx.x;
    KT a = kt_sent();
    for (int rt = 0; rt < TRT; rt++)
        a = kt_merge(a, kt_unpack(colPart[(size_t)rt * MPTS + m]));
    float d1 = __uint_as_float((u32)(a.k1 >> 32));
    float d2 = __uint_as_float((u32)(a.k2 >> 32));
    bck_nn[m] = (int)(u32)a.k1;
    bck_ok[m] = ((d1 / d2) < 1.0f) ? 1 : 0;   // exact ref ratio test, RT=1.0
}

__global__ __launch_bounds__(256) void reduce_rows_final(
    const uint4* __restrict__ rowPart,
    const int* __restrict__ bck_nn, const int* __restrict__ bck_ok,
    float* __restrict__ out)
{
    int n = blockIdx.x * 256 + threadIdx.x;
    KT a = kt_sent();
    for (int ct = 0; ct < TCT; ct++)
        a = kt_merge(a, kt_unpack(rowPart[(size_t)ct * NPTS + n]));
    int fwd  = (int)(u32)a.k1;
    float d1 = __uint_as_float((u32)(a.k1 >> 32));
    float d2 = __uint_as_float((u32)(a.k2 >> 32));
    bool ok  = (d1 / d2) < 1.0f;
    bool mutual = ok && (bck_ok[fwd] != 0) && (bck_nn[fwd] == n);
    int idx0 = mutual ? fwd : -1;
    out[n]             = (float)idx0;                // indices0
    out[NPTS + n]      = -1.0f;                      // matches1 (all -1)
    out[2 * NPTS + n]  = (idx0 > 0) ? 1.0f : 0.0f;   // mscores0 (strict >0 ref quirk)
    out[3 * NPTS + n]  = 0.0f;                       // mscores1
}

extern "C" void kernel_launch(void* const* d_in, const int* in_sizes, int n_in,
                              void* d_out, int out_size, void* d_ws, size_t ws_size,
                              hipStream_t stream)
{
    const float* d0 = (const float*)d_in[0];   // [1, 256, 8192] f32
    const float* d1 = (const float*)d_in[1];   // [1, 256, 8192] f32

    char* ws = (char*)d_ws;
    const size_t matB = (size_t)NPTS * FDIM * sizeof(ushort_t);      // 4 MB
    ushort_t* hiA = (ushort_t*)(ws);
    ushort_t* loA = (ushort_t*)(ws + matB);
    ushort_t* hiB = (ushort_t*)(ws + 2 * matB);
    ushort_t* loB = (ushort_t*)(ws + 3 * matB);
    char* p = ws + 4 * matB;
    const size_t rowBytes = (size_t)TCT * NPTS * sizeof(uint4);      // 8 MB
    const size_t colBytes = (size_t)TRT * MPTS * sizeof(uint4);      // 8 MB
    uint4* rowPart = (uint4*)p;
    uint4* colPart = (uint4*)(p + rowBytes);
    int*   bck_nn  = (int*)(p + rowBytes + colBytes);
    int*   bck_ok  = bck_nn + MPTS;
    int*   flag    = bck_ok + MPTS;

    hipMemsetAsync(flag, 0, sizeof(int), stream);

    dim3 gt(NPTS / 64, FDIM / 64);
    transpose_split<<<gt, 256, 0, stream>>>(d0, hiA, loA, flag, NPTS);
    transpose_split<<<gt, 256, 0, stream>>>(d1, hiB, loB, flag, MPTS);

    dim3 g1(TCT, TRT);
    gemm_top2<<<g1, 256, 0, stream>>>(hiA, loA, hiB, loB, flag, rowPart, colPart);
    reduce_cols<<<MPTS / 256, 256, 0, stream>>>(colPart, bck_nn, bck_ok);
    reduce_rows_final<<<NPTS / 256, 256, 0, stream>>>(rowPart, bck_nn, bck_ok,
                                                      (float*)d_out);
}

// Round 7
// 201.096 us; speedup vs baseline: 3.2913x; 1.4353x over previous
//
#include <hip/hip_runtime.h>
#include <float.h>

#define NPTS 8192
#define MPTS 8192
#define FDIM 256

#define BM 128
#define BN 128
#define BK 32
#define TCT (MPTS / BN)   /* 64 column tiles */
#define TRT (NPTS / BM)   /* 64 row tiles */

typedef unsigned short ushort_t;
typedef unsigned int u32;
typedef unsigned long long u64;
typedef __attribute__((ext_vector_type(8))) short short8;
typedef __attribute__((ext_vector_type(4))) float floatx4;

// ---- packed top-2: key = (c_bits << 32) | idx. c > 0 so uint order == float
// order; u64 compare == lexicographic (c, idx). c = max(1-s, 1e-6) is strictly
// monotone in dist d = 1.414213*sqrt(c); any d-collision (sqrt rounding) gives
// d1==d2 -> ratio==1 -> ok=false under RT=1.0 in BOTH orderings, and NN2's
// index is never output -- so selecting on c and converting c->d only at the
// ratio test yields outputs identical to the reference's d-space top-2.
struct KT { u64 k1, k2; };   // k1 <= k2

__device__ __forceinline__ KT kt_sent() { KT a; a.k1 = ~0ull; a.k2 = ~0ull; return a; }
__device__ __forceinline__ KT kt_of_pair(u64 a, u64 b) {
    KT t; bool c = a < b; t.k1 = c ? a : b; t.k2 = c ? b : a; return t;
}
__device__ __forceinline__ KT kt_merge(KT a, KT b) {
    KT r; bool c = a.k1 < b.k1;
    r.k1 = c ? a.k1 : b.k1;
    u64 x = c ? b.k1 : a.k1;     // max of firsts
    u64 y = c ? a.k2 : b.k2;     // runner-up of winning side
    r.k2 = x < y ? x : y;
    return r;
}
__device__ __forceinline__ uint4 kt_pack(KT a) {
    return make_uint4((u32)a.k1, (u32)(a.k1 >> 32), (u32)a.k2, (u32)(a.k2 >> 32));
}
__device__ __forceinline__ KT kt_unpack(uint4 v) {
    KT a; a.k1 = v.x | ((u64)v.y << 32); a.k2 = v.z | ((u64)v.w << 32); return a;
}
__device__ __forceinline__ u64 shfl_xor_u64(u64 v, int m) {
    u32 lo = __shfl_xor((u32)v, m);
    u32 hi = __shfl_xor((u32)(v >> 32), m);
    return ((u64)hi << 32) | lo;
}
__device__ __forceinline__ u64 mk_key(float c, int idx) {
    return ((u64)__float_as_uint(c) << 32) | (u32)idx;
}

__device__ __forceinline__ float bf2f(ushort_t u) {
    union { u32 i; float f; } v; v.i = ((u32)u) << 16; return v.f;
}
__device__ __forceinline__ ushort_t f2bf_rtne(float x) {
    u32 u = __float_as_uint(x);
    u32 r = u + 0x7FFFu + ((u >> 16) & 1u);
    return (ushort_t)(r >> 16);
}

// -------- fused transpose + hi/lo split for BOTH matrices (z = which) -----
// src f32 [FDIM][N] -> hiT/loT bf16 [N][FDIM]; hi = bf16(x), lo = bf16(x-hi)
// (unscaled: bf16 is a float format, scale carries in the exponent).
__global__ __launch_bounds__(256) void transpose_split(
    const float* __restrict__ s0, const float* __restrict__ s1,
    ushort_t* __restrict__ hi0, ushort_t* __restrict__ lo0,
    ushort_t* __restrict__ hi1, ushort_t* __restrict__ lo1)
{
    __shared__ ushort_t hiS[64][66];
    __shared__ ushort_t loS[64][66];
    const float* src = blockIdx.z ? s1 : s0;
    ushort_t* hiT = blockIdx.z ? hi1 : hi0;
    ushort_t* loT = blockIdx.z ? lo1 : lo0;
    const int t = threadIdx.x;
    const int n0 = blockIdx.x * 64, f0 = blockIdx.y * 64;
#pragma unroll
    for (int p = 0; p < 16; p++) {
        int fl = (t >> 6) + p * 4;
        int nl = t & 63;
        float x = src[(size_t)(f0 + fl) * NPTS + n0 + nl];
        ushort_t hb = f2bf_rtne(x);
        ushort_t lb = f2bf_rtne(x - bf2f(hb));
        hiS[nl][fl] = hb;
        loS[nl][fl] = lb;
    }
    __syncthreads();
#pragma unroll
    for (int p = 0; p < 8; p++) {
        int nl = (t >> 5) + p * 8;
        int fp = (t & 31) * 2;
        u32 hw = (u32)hiS[nl][fp] | ((u32)hiS[nl][fp + 1] << 16);
        u32 lw = (u32)loS[nl][fp] | ((u32)loS[nl][fp + 1] << 16);
        size_t o = (size_t)(n0 + nl) * FDIM + f0 + fp;
        *(u32*)&hiT[o] = hw;
        *(u32*)&loT[o] = lw;
    }
}

#define GLDS(g, l) __builtin_amdgcn_global_load_lds( \
    (const __attribute__((address_space(1))) void*)(g), \
    (__attribute__((address_space(3))) void*)(l), 16, 0, 0)

// -------- fused MFMA GEMM + branchless packed top-2 --------
// LDS chunk swizzle: row r's four 16B k-chunks are stored permuted by
// chunk_pos = chunk_global ^ ((r>>1)&3). Fragment read for (row r, quad q)
// reads pos q ^ ((r>>1)&3); 16 consecutive lanes then start at banks
// {0,16,4,20,8,24,12,28}x2 -> 2-way (free) instead of 8-way conflict.
__global__ __launch_bounds__(256, 2) void gemm_top2(
    const ushort_t* __restrict__ hiA, const ushort_t* __restrict__ loA,
    const ushort_t* __restrict__ hiB, const ushort_t* __restrict__ loB,
    uint4* __restrict__ rowPart, uint4* __restrict__ colPart)
{
    __shared__ char smem[36864];
    ushort_t* Ah = (ushort_t*)smem;                 // 8 KB each
    ushort_t* Bh = (ushort_t*)(smem + 8192);
    ushort_t* Al = (ushort_t*)(smem + 16384);
    ushort_t* Bl = (ushort_t*)(smem + 24576);
    uint4* redC  = (uint4*)(smem + 32768);          // [128][2], 4 KB
    u64* scrK1 = (u64*)smem;                        // epilogue scratch (aliased)
    u64* scrK2 = (u64*)(smem + 16384);

    const int t = threadIdx.x;
    const int lane = t & 63, lc = lane & 15, q = lane >> 4;
    const int w = t >> 6, wx = w & 1, wy = w >> 1;
    const int ctile = blockIdx.x, rtile = blockIdx.y;
    const int n0 = rtile * BM, m0 = ctile * BN;

    floatx4 acc[4][4];
#pragma unroll
    for (int i = 0; i < 4; i++)
#pragma unroll
        for (int j = 0; j < 4; j++) acc[i][j] = (floatx4)0.0f;

    // staging: lane t -> LDS bytes [t*16, t*16+16); LDS row = t>>2, chunk pos
    // = t&3 holds GLOBAL chunk (t&3) ^ ((t>>3)&3)  [swizzle round-trip]
    const int srow = t >> 2;
    const int skoff = (((t & 3) ^ ((t >> 3) & 3))) * 8;
    const size_t sldsOff = (size_t)t * 8;
    // fragment read k-offset (ushorts), lane-constant: pos = q ^ ((lc>>1)&3)
    const int fkoff = (q ^ ((lc >> 1) & 3)) * 8;

    for (int k0 = 0; k0 < FDIM; k0 += BK) {
        if (k0) __syncthreads();
        GLDS(hiA + (size_t)(n0 + srow) * FDIM + k0 + skoff, Ah + sldsOff);
        GLDS(hiA + (size_t)(n0 + srow + 64) * FDIM + k0 + skoff, Ah + 2048 + sldsOff);
        GLDS(hiB + (size_t)(m0 + srow) * FDIM + k0 + skoff, Bh + sldsOff);
        GLDS(hiB + (size_t)(m0 + srow + 64) * FDIM + k0 + skoff, Bh + 2048 + sldsOff);
        GLDS(loA + (size_t)(n0 + srow) * FDIM + k0 + skoff, Al + sldsOff);
        GLDS(loA + (size_t)(n0 + srow + 64) * FDIM + k0 + skoff, Al + 2048 + sldsOff);
        GLDS(loB + (size_t)(m0 + srow) * FDIM + k0 + skoff, Bl + sldsOff);
        GLDS(loB + (size_t)(m0 + srow + 64) * FDIM + k0 + skoff, Bl + 2048 + sldsOff);
        __syncthreads();

        short8 ah[4], bh[4], al[4], bl[4];
#pragma unroll
        for (int i = 0; i < 4; i++) {
            int r = (wy * 64 + i * 16 + lc) * BK;
            ah[i] = *(const short8*)&Ah[r + fkoff];
            al[i] = *(const short8*)&Al[r + fkoff];
        }
#pragma unroll
        for (int j = 0; j < 4; j++) {
            int r = (wx * 64 + j * 16 + lc) * BK;
            bh[j] = *(const short8*)&Bh[r + fkoff];
            bl[j] = *(const short8*)&Bl[r + fkoff];
        }
#pragma unroll
        for (int i = 0; i < 4; i++)
#pragma unroll
            for (int j = 0; j < 4; j++) {
                acc[i][j] = __builtin_amdgcn_mfma_f32_16x16x32_bf16(ah[i], bh[j], acc[i][j], 0, 0, 0);
                acc[i][j] = __builtin_amdgcn_mfma_f32_16x16x32_bf16(ah[i], bl[j], acc[i][j], 0, 0, 0);
                acc[i][j] = __builtin_amdgcn_mfma_f32_16x16x32_bf16(al[i], bh[j], acc[i][j], 0, 0, 0);
            }
    }

    // ---- epilogue: C/D layout row = q*4+reg, col = lane&15 (verified) ----
    KT colT[4];
#pragma unroll
    for (int j = 0; j < 4; j++) colT[j] = kt_sent();
    KT rowT[4][4];

#pragma unroll
    for (int i = 0; i < 4; i++) {
        float cl[4][4];
#pragma unroll
        for (int j = 0; j < 4; j++)
#pragma unroll
            for (int r = 0; r < 4; r++)
                cl[j][r] = fmaxf(1.0f - acc[i][j][r], 1e-6f);
#pragma unroll
        for (int r = 0; r < 4; r++) {
            u64 v0 = mk_key(cl[0][r], m0 + wx * 64 +  0 + lc);
            u64 v1 = mk_key(cl[1][r], m0 + wx * 64 + 16 + lc);
            u64 v2 = mk_key(cl[2][r], m0 + wx * 64 + 32 + lc);
            u64 v3 = mk_key(cl[3][r], m0 + wx * 64 + 48 + lc);
            rowT[i][r] = kt_merge(kt_of_pair(v0, v1), kt_of_pair(v2, v3));
        }
        const int rbase = n0 + wy * 64 + i * 16 + q * 4;
#pragma unroll
        for (int j = 0; j < 4; j++) {
            u64 v0 = mk_key(cl[j][0], rbase + 0);
            u64 v1 = mk_key(cl[j][1], rbase + 1);
            u64 v2 = mk_key(cl[j][2], rbase + 2);
            u64 v3 = mk_key(cl[j][3], rbase + 3);
            colT[j] = kt_merge(colT[j], kt_merge(kt_of_pair(v0, v1), kt_of_pair(v2, v3)));
        }
    }

    // cols: merge across the 4 quads, then stash per (wy, col)
#pragma unroll
    for (int j = 0; j < 4; j++) {
        KT o;
        o.k1 = shfl_xor_u64(colT[j].k1, 16); o.k2 = shfl_xor_u64(colT[j].k2, 16);
        colT[j] = kt_merge(colT[j], o);
        o.k1 = shfl_xor_u64(colT[j].k1, 32); o.k2 = shfl_xor_u64(colT[j].k2, 32);
        colT[j] = kt_merge(colT[j], o);
        if (q == 0) redC[(wx * 64 + j * 16 + lc) * 2 + wy] = kt_pack(colT[j]);
    }

    // rows: two LDS rounds (by wy) over reused staging scratch
#pragma unroll
    for (int round = 0; round < 2; round++) {
        __syncthreads();
        if (wy == round) {
#pragma unroll
            for (int i = 0; i < 4; i++)
#pragma unroll
                for (int r = 0; r < 4; r++) {
                    int row = i * 16 + q * 4 + r;                 // 0..63
                    int col = (lc << 1) | wx;                     // 0..31
                    int slot = (row << 5) | ((col + row) & 31);   // bank swizzle
                    scrK1[slot] = rowT[i][r].k1;
                    scrK2[slot] = rowT[i][r].k2;
                }
        }
        __syncthreads();
        {
            int row = t >> 2, chunk = t & 3;
            KT a = kt_sent();
#pragma unroll
            for (int s = 0; s < 8; s++) {
                int slot = (row << 5) | (chunk << 3) | ((s + row) & 7);
                KT b; b.k1 = scrK1[slot]; b.k2 = scrK2[slot];
                a = kt_merge(a, b);
            }
            KT o;
            o.k1 = shfl_xor_u64(a.k1, 1); o.k2 = shfl_xor_u64(a.k2, 1); a = kt_merge(a, o);
            o.k1 = shfl_xor_u64(a.k1, 2); o.k2 = shfl_xor_u64(a.k2, 2); a = kt_merge(a, o);
            if (chunk == 0)
                rowPart[(size_t)ctile * NPTS + n0 + round * 64 + row] = kt_pack(a);
        }
    }

    __syncthreads();
    if (t < 128) {
        KT m = kt_unpack(redC[t * 2 + 0]);
        m = kt_merge(m, kt_unpack(redC[t * 2 + 1]));
        colPart[(size_t)rtile * MPTS + m0 + t] = kt_pack(m);
    }
}

__global__ __launch_bounds__(256) void reduce_cols(
    const uint4* __restrict__ colPart, int* __restrict__ bck_nn, int* __restrict__ bck_ok)
{
    int m = blockIdx.x * 256 + threadIdx.x;
    KT a = kt_sent();
    for (int rt = 0; rt < TRT; rt++)
        a = kt_merge(a, kt_unpack(colPart[(size_t)rt * MPTS + m]));
    float d1 = 1.414213f * sqrtf(__uint_as_float((u32)(a.k1 >> 32)));
    float d2 = 1.414213f * sqrtf(__uint_as_float((u32)(a.k2 >> 32)));
    bck_nn[m] = (int)(u32)a.k1;
    bck_ok[m] = ((d1 / d2) < 1.0f) ? 1 : 0;   // exact ref ratio test, RT=1.0
}

__global__ __launch_bounds__(256) void reduce_rows_final(
    const uint4* __restrict__ rowPart,
    const int* __restrict__ bck_nn, const int* __restrict__ bck_ok,
    float* __restrict__ out)
{
    int n = blockIdx.x * 256 + threadIdx.x;
    KT a = kt_sent();
    for (int ct = 0; ct < TCT; ct++)
        a = kt_merge(a, kt_unpack(rowPart[(size_t)ct * NPTS + n]));
    int fwd  = (int)(u32)a.k1;
    float d1 = 1.414213f * sqrtf(__uint_as_float((u32)(a.k1 >> 32)));
    float d2 = 1.414213f * sqrtf(__uint_as_float((u32)(a.k2 >> 32)));
    bool ok  = (d1 / d2) < 1.0f;
    bool mutual = ok && (bck_ok[fwd] != 0) && (bck_nn[fwd] == n);
    int idx0 = mutual ? fwd : -1;
    out[n]             = (float)idx0;                // indices0
    out[NPTS + n]      = -1.0f;                      // matches1 (all -1)
    out[2 * NPTS + n]  = (idx0 > 0) ? 1.0f : 0.0f;   // mscores0 (strict >0 ref quirk)
    out[3 * NPTS + n]  = 0.0f;                       // mscores1
}

extern "C" void kernel_launch(void* const* d_in, const int* in_sizes, int n_in,
                              void* d_out, int out_size, void* d_ws, size_t ws_size,
                              hipStream_t stream)
{
    const float* d0 = (const float*)d_in[0];   // [1, 256, 8192] f32
    const float* d1 = (const float*)d_in[1];   // [1, 256, 8192] f32

    char* ws = (char*)d_ws;
    const size_t matB = (size_t)NPTS * FDIM * sizeof(ushort_t);      // 4 MB
    ushort_t* hiA = (ushort_t*)(ws);
    ushort_t* loA = (ushort_t*)(ws + matB);
    ushort_t* hiB = (ushort_t*)(ws + 2 * matB);
    ushort_t* loB = (ushort_t*)(ws + 3 * matB);
    char* p = ws + 4 * matB;
    const size_t rowBytes = (size_t)TCT * NPTS * sizeof(uint4);      // 8 MB
    const size_t colBytes = (size_t)TRT * MPTS * sizeof(uint4);      // 8 MB
    uint4* rowPart = (uint4*)p;
    uint4* colPart = (uint4*)(p + rowBytes);
    int*   bck_nn  = (int*)(p + rowBytes + colBytes);
    int*   bck_ok  = bck_nn + MPTS;

    dim3 gt(NPTS / 64, FDIM / 64, 2);
    transpose_split<<<gt, 256, 0, stream>>>(d0, d1, hiA, loA, hiB, loB);

    dim3 g1(TCT, TRT);
    gemm_top2<<<g1, 256, 0, stream>>>(hiA, loA, hiB, loB, rowPart, colPart);
    reduce_cols<<<MPTS / 256, 256, 0, stream>>>(colPart, bck_nn, bck_ok);
    reduce_rows_final<<<NPTS / 256, 256, 0, stream>>>(rowPart, bck_nn, bck_ok,
                                                      (float*)d_out);
}

// Round 8
// 183.187 us; speedup vs baseline: 3.6130x; 1.0978x over previous
//
#include <hip/hip_runtime.h>
#include <float.h>

#define NPTS 8192
#define MPTS 8192
#define FDIM 256

#define BM 128
#define BN 128
#define BK 32
#define TCT (MPTS / BN)   /* 64 column tiles */
#define TRT (NPTS / BM)   /* 64 row tiles */

typedef unsigned short ushort_t;
typedef unsigned int u32;
typedef __attribute__((ext_vector_type(8))) short short8;
typedef __attribute__((ext_vector_type(4))) float floatx4;

// ---- top-2-by-similarity state. Selection is on RAW s (max); the clamp
// c = max(1-s, 1e-6) and dist = 1.414213*sqrt(c) are applied only at the
// ratio test. Output-equivalence to the reference's d-space stable top-2:
// c is monotone non-increasing in s (strictly where unclamped), and ANY case
// where orderings could differ (value ties from clamp or sqrt rounding, or
// index tie-break) forces d1==d2 -> ratio==1 -> ok=false under RT=1.0 on that
// side -> output -1 / mutual=false regardless of index; bck_nn is consulted
// only under bck_ok=true (no tie); NN2's index is never output.
struct T2 { float s1, s2; int i1; };   // s1 >= s2

__device__ __forceinline__ T2 t2_sent() { T2 a; a.s1 = -FLT_MAX; a.s2 = -FLT_MAX; a.i1 = 0; return a; }

__device__ __forceinline__ T2 t2_merge(T2 a, T2 b) {
    T2 r;
    r.s1 = fmaxf(a.s1, b.s1);
    r.i1 = (b.s1 > a.s1) ? b.i1 : a.i1;
    r.s2 = fmaxf(fminf(a.s1, b.s1), fmaxf(a.s2, b.s2));
    return r;
}
// top-2 of 4 candidates (values v0..v3, indices i0..i3)
__device__ __forceinline__ T2 t2_make4(float v0, float v1, float v2, float v3,
                                       int i0, int i1_, int i2, int i3) {
    float lo01 = fminf(v0, v1), hi01 = fmaxf(v0, v1);
    float lo23 = fminf(v2, v3), hi23 = fmaxf(v2, v3);
    int a01 = (v1 > v0) ? i1_ : i0;
    int a23 = (v3 > v2) ? i3 : i2;
    T2 r;
    r.s1 = fmaxf(hi01, hi23);
    r.i1 = (hi23 > hi01) ? a23 : a01;
    r.s2 = fmaxf(fminf(hi01, hi23), fmaxf(lo01, lo23));
    return r;
}
__device__ __forceinline__ float4 t2_pack(T2 a) {
    return make_float4(a.s1, a.s2, __int_as_float(a.i1), 0.0f);
}
__device__ __forceinline__ T2 t2_unpack(float4 v) {
    T2 a; a.s1 = v.x; a.s2 = v.y; a.i1 = __float_as_int(v.z); return a;
}
__device__ __forceinline__ T2 t2_shfl_xor(T2 a, int m) {
    T2 r; r.s1 = __shfl_xor(a.s1, m); r.s2 = __shfl_xor(a.s2, m); r.i1 = __shfl_xor(a.i1, m);
    return r;
}

__device__ __forceinline__ float bf2f(ushort_t u) {
    union { u32 i; float f; } v; v.i = ((u32)u) << 16; return v.f;
}
__device__ __forceinline__ ushort_t f2bf_rtne(float x) {
    u32 u = __float_as_uint(x);
    u32 r = u + 0x7FFFu + ((u >> 16) & 1u);
    return (ushort_t)(r >> 16);
}

// -------- fused transpose + hi/lo split for BOTH matrices (z = which) -----
__global__ __launch_bounds__(256) void transpose_split(
    const float* __restrict__ s0, const float* __restrict__ s1,
    ushort_t* __restrict__ hi0, ushort_t* __restrict__ lo0,
    ushort_t* __restrict__ hi1, ushort_t* __restrict__ lo1)
{
    __shared__ ushort_t hiS[64][66];
    __shared__ ushort_t loS[64][66];
    const float* src = blockIdx.z ? s1 : s0;
    ushort_t* hiT = blockIdx.z ? hi1 : hi0;
    ushort_t* loT = blockIdx.z ? lo1 : lo0;
    const int t = threadIdx.x;
    const int n0 = blockIdx.x * 64, f0 = blockIdx.y * 64;
#pragma unroll
    for (int p = 0; p < 16; p++) {
        int fl = (t >> 6) + p * 4;
        int nl = t & 63;
        float x = src[(size_t)(f0 + fl) * NPTS + n0 + nl];
        ushort_t hb = f2bf_rtne(x);
        ushort_t lb = f2bf_rtne(x - bf2f(hb));
        hiS[nl][fl] = hb;
        loS[nl][fl] = lb;
    }
    __syncthreads();
#pragma unroll
    for (int p = 0; p < 8; p++) {
        int nl = (t >> 5) + p * 8;
        int fp = (t & 31) * 2;
        u32 hw = (u32)hiS[nl][fp] | ((u32)hiS[nl][fp + 1] << 16);
        u32 lw = (u32)loS[nl][fp] | ((u32)loS[nl][fp + 1] << 16);
        size_t o = (size_t)(n0 + nl) * FDIM + f0 + fp;
        *(u32*)&hiT[o] = hw;
        *(u32*)&loT[o] = lw;
    }
}

#define GLDS(g, l) __builtin_amdgcn_global_load_lds( \
    (const __attribute__((address_space(1))) void*)(g), \
    (__attribute__((address_space(3))) void*)(l), 16, 0, 0)

// -------- fused MFMA GEMM + branchless f32 top-2 --------
__global__ __launch_bounds__(256, 2) void gemm_top2(
    const ushort_t* __restrict__ hiA, const ushort_t* __restrict__ loA,
    const ushort_t* __restrict__ hiB, const ushort_t* __restrict__ loB,
    float4* __restrict__ rowPart, float4* __restrict__ colPart)
{
    __shared__ char smem[36864];
    ushort_t* Ah = (ushort_t*)smem;                 // 8 KB each (staging)
    ushort_t* Bh = (ushort_t*)(smem + 8192);
    ushort_t* Al = (ushort_t*)(smem + 16384);
    ushort_t* Bl = (ushort_t*)(smem + 24576);
    // epilogue aliases (all uses strictly after staging is done + barrier):
    float* scrS1 = (float*)smem;                    // 64*33*4 = 8448 B
    float* scrS2 = (float*)(smem + 8448);
    int*   scrI  = (int*)(smem + 16896);            // ends 25344
    float4* redC = (float4*)(smem + 25600);         // 128*2*16 = 4096 B

    const int t = threadIdx.x;
    const int lane = t & 63, lc = lane & 15, q = lane >> 4;
    const int w = t >> 6, wx = w & 1, wy = w >> 1;
    const int ctile = blockIdx.x, rtile = blockIdx.y;
    const int n0 = rtile * BM, m0 = ctile * BN;

    floatx4 acc[4][4];
#pragma unroll
    for (int i = 0; i < 4; i++)
#pragma unroll
        for (int j = 0; j < 4; j++) acc[i][j] = (floatx4)0.0f;

    // staging (proven round 7): chunk swizzle pos = chunk ^ ((row>>1)&3)
    const int srow = t >> 2;
    const int skoff = (((t & 3) ^ ((t >> 3) & 3))) * 8;
    const size_t sldsOff = (size_t)t * 8;
    const int fkoff = (q ^ ((lc >> 1) & 3)) * 8;

    for (int k0 = 0; k0 < FDIM; k0 += BK) {
        if (k0) __syncthreads();
        GLDS(hiA + (size_t)(n0 + srow) * FDIM + k0 + skoff, Ah + sldsOff);
        GLDS(hiA + (size_t)(n0 + srow + 64) * FDIM + k0 + skoff, Ah + 2048 + sldsOff);
        GLDS(hiB + (size_t)(m0 + srow) * FDIM + k0 + skoff, Bh + sldsOff);
        GLDS(hiB + (size_t)(m0 + srow + 64) * FDIM + k0 + skoff, Bh + 2048 + sldsOff);
        GLDS(loA + (size_t)(n0 + srow) * FDIM + k0 + skoff, Al + sldsOff);
        GLDS(loA + (size_t)(n0 + srow + 64) * FDIM + k0 + skoff, Al + 2048 + sldsOff);
        GLDS(loB + (size_t)(m0 + srow) * FDIM + k0 + skoff, Bl + sldsOff);
        GLDS(loB + (size_t)(m0 + srow + 64) * FDIM + k0 + skoff, Bl + 2048 + sldsOff);
        __syncthreads();

        short8 ah[4], bh[4], al[4], bl[4];
#pragma unroll
        for (int i = 0; i < 4; i++) {
            int r = (wy * 64 + i * 16 + lc) * BK;
            ah[i] = *(const short8*)&Ah[r + fkoff];
            al[i] = *(const short8*)&Al[r + fkoff];
        }
#pragma unroll
        for (int j = 0; j < 4; j++) {
            int r = (wx * 64 + j * 16 + lc) * BK;
            bh[j] = *(const short8*)&Bh[r + fkoff];
            bl[j] = *(const short8*)&Bl[r + fkoff];
        }
#pragma unroll
        for (int i = 0; i < 4; i++)
#pragma unroll
            for (int j = 0; j < 4; j++) {
                acc[i][j] = __builtin_amdgcn_mfma_f32_16x16x32_bf16(ah[i], bh[j], acc[i][j], 0, 0, 0);
                acc[i][j] = __builtin_amdgcn_mfma_f32_16x16x32_bf16(ah[i], bl[j], acc[i][j], 0, 0, 0);
                acc[i][j] = __builtin_amdgcn_mfma_f32_16x16x32_bf16(al[i], bh[j], acc[i][j], 0, 0, 0);
            }
    }

    // ---- epilogue: C/D layout row = q*4+reg, col = lane&15 (verified) ----
    T2 colT[4];
#pragma unroll
    for (int j = 0; j < 4; j++) colT[j] = t2_sent();
    T2 rowT[4][4];

    const int cb = m0 + wx * 64 + lc;
#pragma unroll
    for (int i = 0; i < 4; i++) {
        // rows: per r, top-2 over the 4 j-columns
#pragma unroll
        for (int r = 0; r < 4; r++)
            rowT[i][r] = t2_make4(acc[i][0][r], acc[i][1][r], acc[i][2][r], acc[i][3][r],
                                  cb, cb + 16, cb + 32, cb + 48);
        // cols: per j, top-2 over the 4 r-rows, fold into running colT
        const int rb = n0 + wy * 64 + i * 16 + q * 4;
#pragma unroll
        for (int j = 0; j < 4; j++)
            colT[j] = t2_merge(colT[j],
                t2_make4(acc[i][j][0], acc[i][j][1], acc[i][j][2], acc[i][j][3],
                         rb, rb + 1, rb + 2, rb + 3));
    }

    // cols: merge across the 4 quads (same column, different row-quarters)
#pragma unroll
    for (int j = 0; j < 4; j++) {
        colT[j] = t2_merge(colT[j], t2_shfl_xor(colT[j], 16));
        colT[j] = t2_merge(colT[j], t2_shfl_xor(colT[j], 32));
        if (q == 0) redC[(wx * 64 + j * 16 + lc) * 2 + wy] = t2_pack(colT[j]);
    }

    // rows: two LDS rounds (by wy). Writer position p = (col+row+9q)&31 is a
    // per-row bijection (q fixed per row); reader reads all 32 positions.
    // Both phases land as uniform 2-way b32 bank access (free).
#pragma unroll
    for (int round = 0; round < 2; round++) {
        __syncthreads();
        if (wy == round) {
#pragma unroll
            for (int i = 0; i < 4; i++)
#pragma unroll
                for (int r = 0; r < 4; r++) {
                    int row = i * 16 + q * 4 + r;                 // 0..63
                    int col = (lc << 1) | wx;                     // 0..31
                    int slot = row * 33 + ((col + row + 9 * q) & 31);
                    scrS1[slot] = rowT[i][r].s1;
                    scrS2[slot] = rowT[i][r].s2;
                    scrI[slot]  = rowT[i][r].i1;
                }
        }
        __syncthreads();
        {
            int row = t >> 2, chunk = t & 3;
            T2 a = t2_sent();
#pragma unroll
            for (int s = 0; s < 8; s++) {
                int slot = row * 33 + ((chunk << 3) | s);
                T2 b; b.s1 = scrS1[slot]; b.s2 = scrS2[slot]; b.i1 = scrI[slot];
                a = t2_merge(a, b);
            }
            a = t2_merge(a, t2_shfl_xor(a, 1));
            a = t2_merge(a, t2_shfl_xor(a, 2));
            if (chunk == 0)
                rowPart[(size_t)ctile * NPTS + n0 + round * 64 + row] = t2_pack(a);
        }
    }

    __syncthreads();
    if (t < 128) {
        T2 m = t2_unpack(redC[t * 2 + 0]);
        m = t2_merge(m, t2_unpack(redC[t * 2 + 1]));
        colPart[(size_t)rtile * MPTS + m0 + t] = t2_pack(m);
    }
}

// -------- parallel partial reduction: 128 blocks, 4 sub-reducers/point ----
__global__ __launch_bounds__(256) void reduce_cols(
    const float4* __restrict__ colPart, int* __restrict__ bck_nn, int* __restrict__ bck_ok)
{
    __shared__ float4 sh[4][64];
    const int t = threadIdx.x, ml = t & 63, sub = t >> 6;
    const int m = blockIdx.x * 64 + ml;
    T2 a = t2_sent();
#pragma unroll
    for (int k = 0; k < 16; k++)
        a = t2_merge(a, t2_unpack(colPart[(size_t)(sub * 16 + k) * MPTS + m]));
    sh[sub][ml] = t2_pack(a);
    __syncthreads();
    if (t < 64) {
        T2 r = t2_unpack(sh[0][t]);
        r = t2_merge(r, t2_unpack(sh[1][t]));
        r = t2_merge(r, t2_unpack(sh[2][t]));
        r = t2_merge(r, t2_unpack(sh[3][t]));
        float c1 = fmaxf(1.0f - r.s1, 1e-6f), c2 = fmaxf(1.0f - r.s2, 1e-6f);
        float d1 = 1.414213f * sqrtf(c1), d2 = 1.414213f * sqrtf(c2);
        int mm = blockIdx.x * 64 + t;
        bck_nn[mm] = r.i1;
        bck_ok[mm] = ((d1 / d2) < 1.0f) ? 1 : 0;   // exact ref ratio test, RT=1.0
    }
}

__global__ __launch_bounds__(256) void reduce_rows_final(
    const float4* __restrict__ rowPart,
    const int* __restrict__ bck_nn, const int* __restrict__ bck_ok,
    float* __restrict__ out)
{
    __shared__ float4 sh[4][64];
    const int t = threadIdx.x, nl = t & 63, sub = t >> 6;
    const int n = blockIdx.x * 64 + nl;
    T2 a = t2_sent();
#pragma unroll
    for (int k = 0; k < 16; k++)
        a = t2_merge(a, t2_unpack(rowPart[(size_t)(sub * 16 + k) * NPTS + n]));
    sh[sub][nl] = t2_pack(a);
    __syncthreads();
    if (t < 64) {
        T2 r = t2_unpack(sh[0][t]);
        r = t2_merge(r, t2_unpack(sh[1][t]));
        r = t2_merge(r, t2_unpack(sh[2][t]));
        r = t2_merge(r, t2_unpack(sh[3][t]));
        float c1 = fmaxf(1.0f - r.s1, 1e-6f), c2 = fmaxf(1.0f - r.s2, 1e-6f);
        float d1 = 1.414213f * sqrtf(c1), d2 = 1.414213f * sqrtf(c2);
        int fwd = r.i1;
        bool ok = (d1 / d2) < 1.0f;
        bool mutual = ok && (bck_ok[fwd] != 0) && (bck_nn[fwd] == (blockIdx.x * 64 + t));
        int idx0 = mutual ? fwd : -1;
        int nn = blockIdx.x * 64 + t;
        out[nn]             = (float)idx0;                // indices0
        out[NPTS + nn]      = -1.0f;                      // matches1 (all -1)
        out[2 * NPTS + nn]  = (idx0 > 0) ? 1.0f : 0.0f;   // mscores0 (strict >0 ref quirk)
        out[3 * NPTS + nn]  = 0.0f;                       // mscores1
    }
}

extern "C" void kernel_launch(void* const* d_in, const int* in_sizes, int n_in,
                              void* d_out, int out_size, void* d_ws, size_t ws_size,
                              hipStream_t stream)
{
    const float* d0 = (const float*)d_in[0];   // [1, 256, 8192] f32
    const float* d1 = (const float*)d_in[1];   // [1, 256, 8192] f32

    char* ws = (char*)d_ws;
    const size_t matB = (size_t)NPTS * FDIM * sizeof(ushort_t);      // 4 MB
    ushort_t* hiA = (ushort_t*)(ws);
    ushort_t* loA = (ushort_t*)(ws + matB);
    ushort_t* hiB = (ushort_t*)(ws + 2 * matB);
    ushort_t* loB = (ushort_t*)(ws + 3 * matB);
    char* p = ws + 4 * matB;
    const size_t rowBytes = (size_t)TCT * NPTS * sizeof(float4);     // 8 MB
    const size_t colBytes = (size_t)TRT * MPTS * sizeof(float4);     // 8 MB
    float4* rowPart = (float4*)p;
    float4* colPart = (float4*)(p + rowBytes);
    int*    bck_nn  = (int*)(p + rowBytes + colBytes);
    int*    bck_ok  = bck_nn + MPTS;

    dim3 gt(NPTS / 64, FDIM / 64, 2);
    transpose_split<<<gt, 256, 0, stream>>>(d0, d1, hiA, loA, hiB, loB);

    dim3 g1(TCT, TRT);
    gemm_top2<<<g1, 256, 0, stream>>>(hiA, loA, hiB, loB, rowPart, colPart);
    reduce_cols<<<MPTS / 64, 256, 0, stream>>>(colPart, bck_nn, bck_ok);
    reduce_rows_final<<<NPTS / 64, 256, 0, stream>>>(rowPart, bck_nn, bck_ok,
                                                     (float*)d_out);
}